// Round 4
// baseline (121.723 us; speedup 1.0000x reference)
//
#include <hip/hip_runtime.h>

#define BB    4
#define CINT  64
#define HH    128
#define WW    128
#define COUT  64
#define DGN   8
#define CG    8
#define KKN   9
#define HO    128
#define WO    128
#define HOWO  16384
#define HWSZ  (HH * WW)
#define NKT   18           // 32-K weight chunks (prep_w layout)
#define NCH   9            // 64-K col chunks in dcn_mfma
#define CROW  72           // 64 + 8 pad ushorts (144B rows, 16B-aligned)

typedef __bf16 bf16x8 __attribute__((ext_vector_type(8)));
typedef float  f32x4  __attribute__((ext_vector_type(4)));

static __device__ __forceinline__ ushort f2bf(float f) {
    unsigned u = __builtin_bit_cast(unsigned, f);
    u += 0x7fffu + ((u >> 16) & 1u);      // round-to-nearest-even
    return (ushort)(u >> 16);
}
static __device__ __forceinline__ float bf2f(ushort u) {
    return __builtin_bit_cast(float, (unsigned)u << 16);
}

// ---- prep 1: weights into MFMA A-fragment order, bf16.
// [kt(18)][mtile(4)][lane(64)] x 8 bf16. A[m=lane&15][k=(lane>>4)*8+j],
// o = mtile*16+m, global K = kt*32 + (lane>>4)*8 + j, K order k=(g*9+kk)*8+c.
__global__ void prep_w(const float* __restrict__ wgt, uint4* __restrict__ wout) {
    int i = blockIdx.x * 256 + threadIdx.x;     // 0..4607
    if (i >= NKT * 4 * 64) return;
    int lane = i & 63;
    int mt   = (i >> 6) & 3;
    int kt   = i >> 8;
    int m = lane & 15, quad = lane >> 4;
    int o = mt * 16 + m;
    union { ushort u[8]; uint4 v; } pk;
#pragma unroll
    for (int j = 0; j < 8; ++j) {
        int k   = kt * 32 + quad * 8 + j;
        int gkk = k >> 3, c = k & 7;
        int g   = gkk / 9, kk = gkk - 9 * g;
        pk.u[j] = f2bf(wgt[(o * CINT + g * CG + c) * KKN + kk]);
    }
    wout[i] = pk.v;
}

// ---- prep 2: x [B, DG*CG, H, W] f32 -> xh [B, DG, H, W, CG] bf16 (16B granules)
__global__ void prep_x(const float* __restrict__ x, uint4* __restrict__ xh) {
    int i  = blockIdx.x * 256 + threadIdx.x;    // over B*DG*H*W = 524288
    int yx = i & (HWSZ - 1);
    int bg = i >> 14;
    const float* xp = x + (size_t)bg * CG * HWSZ + yx;
    union { ushort u[8]; uint4 v; } pk;
#pragma unroll
    for (int c = 0; c < CG; ++c) pk.u[c] = f2bf(xp[c * HWSZ]);
    xh[i] = pk.v;
}

// ---- main: 32 pixels x 64 outs per block, 256 threads (4 waves).
// Chunks of 64 K; all threads produce: thread=(px=tid&31, q=tid>>5), gkk=ch*8+q.
// Wave w consumes: n-half nh=w&1 (pixels nh*16..+16), m-pair mp=w>>1 (tiles 2mp,2mp+1).
__global__ __launch_bounds__(256, 8) void dcn_mfma(
    const uint4* __restrict__ xh, const float* __restrict__ off,
    const uint4* __restrict__ wq, const float* __restrict__ bias,
    float* __restrict__ out)
{
    __shared__ __align__(16) ushort col[2][32][CROW];   // 2*32*144B = 9216B
    __shared__ float sbias[COUT];

    const int tid  = threadIdx.x;
    const int wave = tid >> 6;
    const int lane = tid & 63;

    const int bid  = blockIdx.x;
    const int tile = ((bid & 7) << 8) | (bid >> 3);   // XCD-contiguous spans
    const int pix_base = tile * 32;
    const int b        = pix_base >> 14;
    const int rem_base = pix_base & 16383;

    // producer coordinates
    const int ppx = tid & 31;
    const int q   = tid >> 5;          // 0..7
    const int rem = rem_base + ppx;
    const int ho = rem >> 7, wo = rem & 127;
    const float fy0 = (float)(ho - 1);
    const float fx0 = (float)(wo - 1);

    if (tid < COUT) sbias[tid] = bias[tid];

    f32x4 acc[2];
    acc[0] = (f32x4){0.f, 0.f, 0.f, 0.f};
    acc[1] = (f32x4){0.f, 0.f, 0.f, 0.f};

    auto produce = [&](int ch) {
        int gkk = ch * 8 + q;                 // 0..71
        int g = gkk / 9, kk = gkk - 9 * g;
        const float* offp = off + ((size_t)((b * DGN + g) * KKN + kk) * 2) * HOWO + rem;
        float dy = offp[0];
        float dx = offp[HOWO];
        float py  = fy0 + (float)(kk / 3) + dy;
        float pxx = fx0 + (float)(kk - (kk / 3) * 3) + dx;
        float y0f = floorf(py), x0f = floorf(pxx);
        int y0 = (int)y0f, x0 = (int)x0f;
        float ly = py - y0f, lx = pxx - x0f;
        float hy = 1.f - ly, hx = 1.f - lx;
        float w00 = hy * hx, w01 = hy * lx, w10 = ly * hx, w11 = ly * lx;
        int y1 = y0 + 1, x1 = x0 + 1;
        bool vy0 = (unsigned)y0 < (unsigned)HH, vy1 = (unsigned)y1 < (unsigned)HH;
        bool vx0 = (unsigned)x0 < (unsigned)WW, vx1 = (unsigned)x1 < (unsigned)WW;
        if (!(vy0 && vx0)) w00 = 0.f;
        if (!(vy0 && vx1)) w01 = 0.f;
        if (!(vy1 && vx0)) w10 = 0.f;
        if (!(vy1 && vx1)) w11 = 0.f;
        int y0c = min(max(y0, 0), HH - 1), y1c = min(max(y1, 0), HH - 1);
        int x0c = min(max(x0, 0), WW - 1), x1c = min(max(x1, 0), WW - 1);
        const uint4* xgp = xh + (size_t)(b * DGN + g) * HWSZ;
        uint4 q00 = xgp[y0c * WW + x0c];
        uint4 q01 = xgp[y0c * WW + x1c];
        uint4 q10 = xgp[y1c * WW + x0c];
        uint4 q11 = xgp[y1c * WW + x1c];
        const ushort* u00 = (const ushort*)&q00;
        const ushort* u01 = (const ushort*)&q01;
        const ushort* u10 = (const ushort*)&q10;
        const ushort* u11 = (const ushort*)&q11;
        union { ushort u[8]; uint4 v; } pk;
#pragma unroll
        for (int c = 0; c < CG; ++c) {
            float v = w00 * bf2f(u00[c]) + w01 * bf2f(u01[c])
                    + w10 * bf2f(u10[c]) + w11 * bf2f(u11[c]);
            pk.u[c] = f2bf(v);
        }
        *(uint4*)&col[ch & 1][ppx][q * 8] = pk.v;
    };

    produce(0);

    // consumer coordinates
    const int n = lane & 15, quad = lane >> 4;
    const int nh = wave & 1, mp = wave >> 1;
    const int brow = nh * 16 + n;

    for (int ch = 0; ch < NCH; ++ch) {
        __syncthreads();
        bf16x8 bf0 = *(const bf16x8*)&col[ch & 1][brow][quad * 8];
        bf16x8 bf1 = *(const bf16x8*)&col[ch & 1][brow][32 + quad * 8];
        const int kt0 = ch * 2;
#pragma unroll
        for (int ti = 0; ti < 2; ++ti) {
            const int mt = mp * 2 + ti;
            bf16x8 a0 = __builtin_bit_cast(bf16x8, wq[(kt0 * 4 + mt) * 64 + lane]);
            bf16x8 a1 = __builtin_bit_cast(bf16x8, wq[((kt0 + 1) * 4 + mt) * 64 + lane]);
            acc[ti] = __builtin_amdgcn_mfma_f32_16x16x32_bf16(a0, bf0, acc[ti], 0, 0, 0);
            acc[ti] = __builtin_amdgcn_mfma_f32_16x16x32_bf16(a1, bf1, acc[ti], 0, 0, 0);
        }
        if (ch + 1 < NCH) produce(ch + 1);
    }

    // C/D layout: col = lane&15 (pixel), row = (lane>>4)*4 + reg (out channel)
    const int rem_out = rem_base + nh * 16 + n;
    float* outp = out + (size_t)b * COUT * HOWO + rem_out;
#pragma unroll
    for (int ti = 0; ti < 2; ++ti) {
#pragma unroll
        for (int r = 0; r < 4; ++r) {
            int o = (mp * 2 + ti) * 16 + quad * 4 + r;
            outp[(size_t)o * HOWO] = acc[ti][r] + sbias[o];
        }
    }
}

extern "C" void kernel_launch(void* const* d_in, const int* in_sizes, int n_in,
                              void* d_out, int out_size, void* d_ws, size_t ws_size,
                              hipStream_t stream) {
    const float* x    = (const float*)d_in[0];
    const float* off  = (const float*)d_in[1];
    const float* wgt  = (const float*)d_in[2];
    const float* bias = (const float*)d_in[3];
    float* out = (float*)d_out;

    uint4* xh = (uint4*)d_ws;                             // 8,388,608 B
    uint4* wq = (uint4*)((char*)d_ws + 8388608);          // 73,728 B

    prep_x<<<dim3(BB * DGN * HWSZ / 256), dim3(256), 0, stream>>>(x, xh);
    prep_w<<<dim3(NKT), dim3(256), 0, stream>>>(wgt, wq);
    dcn_mfma<<<dim3(BB * HO * WO / 32), dim3(256), 0, stream>>>(xh, off, wq, bias, out);
}